// Round 12
// baseline (390.362 us; speedup 1.0000x reference)
//
#include <hip/hip_runtime.h>

#define NCV 100000
#define NTV 300000
#define NPV 50000
#define DD 128
#define OUTC 10
#define EMV 300000
#define EIV 600000
#define YST 16
#define NHEADS (NCV + NPV + 2 * NTV)
#define NEB ((EIV + 255) / 256)          // 2344 edge blocks
#define PTB ((3 * 1280 * 64) / 256)      // 960 prepT blocks (wave-per-output)
#define NQB 560                          // prepQ-direct blocks (2240 waves, 4 outputs each)
#define GYB ((NCV + NPV + 255) / 256)    // gather_y blocks

__device__ __forceinline__ float i2f(int v) { return __int_as_float(v); }

// ---------------- d2: fused build (r10 body) + prepT tail + prepQ-direct tail ---------
// Build blocks [0,NEB): both-side exchs in-thread (MLP-overlapped), fat 48B c/p-nodes
//   {next,xt0..2}{xt3..6}{xt7,0,0,0}, thin int2 t-nodes {next,src}. (82us, r10-measured)
// prepT blocks [NEB,NEB+PTB): T1=Wn10@Wout T2=Wn12@Wout T3=0.5(Wr10+Wr12)@Wout.
// prepQ blocks [NEB+PTB,..): Q_q[k,o] = sum_n Wq[k,n] * (sum_m Mq[n,m]*Wout[m,o])
//   computed DIRECTLY from raw weights (no T dependency; redundant inner recompute is
//   ~37M MAC + 143MB L2-hot reads, hidden under the fabric-bound build window).
__global__ __launch_bounds__(256) void build_mega(
    const int* __restrict__ ems, const int* __restrict__ emd,
    const int* __restrict__ eis, const int* __restrict__ eid,
    const float* __restrict__ xt,
    int* __restrict__ head_c, int* __restrict__ head_p,
    int* __restrict__ heads_t,
    int4* __restrict__ cnm, int4* __restrict__ cni,
    int2* __restrict__ tn_m, int2* __restrict__ tn_i,
    const float* __restrict__ Wn, const float* __restrict__ Wr,
    const float* __restrict__ Wout,
    float* __restrict__ T, float* __restrict__ Q) {
  int b = blockIdx.x;
  int tid = threadIdx.x;

  const float* Wn00 = Wn;               const float* Wn01 = Wn + 16384;
  const float* Wn02 = Wn + 2 * 16384;   const float* Wn03 = Wn + 3 * 16384;
  const float* Wn10 = Wn + 4 * 16384;   const float* Wn12 = Wn + 6 * 16384;
  const float* Wr00 = Wr;               const float* Wr01 = Wr + 16384;
  const float* Wr02 = Wr + 2 * 16384;   const float* Wr03 = Wr + 3 * 16384;
  const float* Wr10 = Wr + 4 * 16384;   const float* Wr12 = Wr + 6 * 16384;

  if (b < NEB) {
    int e = b * 256 + tid;
    if (e < EMV) {
      int c = ems[e], t = emd[e];
      int cn = atomicExch(&head_c[c], e);
      int tn = atomicExch(&heads_t[2 * t], e);
      const int4* xr = (const int4*)(xt + (size_t)t * 8);
      int4 x0 = xr[0], x1 = xr[1];
      size_t bb = 4 * (size_t)e;
      cnm[bb]     = make_int4(cn, x0.x, x0.y, x0.z);
      cnm[bb + 1] = make_int4(x0.w, x1.x, x1.y, x1.z);
      cnm[bb + 2] = make_int4(x1.w, 0, 0, 0);
      tn_m[e] = make_int2(tn, c);
    }
    if (e < EIV) {
      int p = eis[e], t = eid[e];
      int pn = atomicExch(&head_p[p], e);
      int tn = atomicExch(&heads_t[2 * t + 1], e);
      const int4* xr = (const int4*)(xt + (size_t)t * 8);
      int4 x0 = xr[0], x1 = xr[1];
      size_t bb = 4 * (size_t)e;
      cni[bb]     = make_int4(pn, x0.x, x0.y, x0.z);
      cni[bb + 1] = make_int4(x0.w, x1.x, x1.y, x1.z);
      cni[bb + 2] = make_int4(x1.w, 0, 0, 0);
      tn_i[e] = make_int2(tn, p);
    }
    return;
  }

  if (b < NEB + PTB) {
    // prepT: wave-per-output (verbatim r10)
    int gw = ((b - NEB) * 256 + tid) >> 6;
    int lane = tid & 63;
    if (gw >= 3 * 1280) return;
    int mat = gw / 1280, r = gw % 1280, n = r / 10, o = r % 10;
    float s = 0.f;
    #pragma unroll
    for (int mi = 0; mi < 2; ++mi) {
      int m = lane + mi * 64;
      float w;
      if (mat == 0) w = Wn10[n * 128 + m];
      else if (mat == 1) w = Wn12[n * 128 + m];
      else w = 0.5f * (Wr10[n * 128 + m] + Wr12[n * 128 + m]);
      s += w * Wout[m * 10 + o];
    }
    #pragma unroll
    for (int d = 32; d; d >>= 1) s += __shfl_xor(s, d);
    if (lane == 0) T[gw] = s;
    return;
  }

  // prepQ-direct: grid-stride wave-per-output, Wout staged in LDS
  __shared__ float sWo[1280];
  for (int i = tid; i < 1280; i += 256) sWo[i] = Wout[i];
  __syncthreads();
  int wid = ((b - NEB - PTB) * 256 + tid) >> 6;
  int lane = tid & 63;
  for (int gw = wid; gw < 7 * 1280; gw += NQB * 4) {
    int q = gw / 1280, r = gw % 1280, k = r / 10, o = r % 10;
    const float* Wq1; const float* Wq2 = nullptr;
    switch (q) {
      case 0: Wq1 = Wn01; break;
      case 1: Wq1 = Wr01; break;
      case 2: Wq1 = Wn03; break;
      case 3: Wq1 = Wr03; break;
      case 4: Wq1 = Wn00; break;
      case 5: Wq1 = Wn02; break;
      default: Wq1 = Wr00; Wq2 = Wr02; break;
    }
    const float* M1; const float* M2 = nullptr;
    if (q < 2) M1 = Wn10;
    else if (q < 4) M1 = Wn12;
    else { M1 = Wr10; M2 = Wr12; }
    float s = 0.f;
    #pragma unroll
    for (int ni = 0; ni < 2; ++ni) {
      int n = lane + ni * 64;
      const float4* mr = (const float4*)(M1 + n * 128);
      const float4* mr2 = M2 ? (const float4*)(M2 + n * 128) : nullptr;
      float t = 0.f;
      for (int m4 = 0; m4 < 32; ++m4) {
        float4 a = mr[m4];
        if (mr2) {
          float4 c = mr2[m4];
          a.x = 0.5f * (a.x + c.x); a.y = 0.5f * (a.y + c.y);
          a.z = 0.5f * (a.z + c.z); a.w = 0.5f * (a.w + c.w);
        }
        const float* wo = &sWo[m4 * 40 + o];
        t += a.x * wo[0] + a.y * wo[10] + a.z * wo[20] + a.w * wo[30];
      }
      float w = Wq1[k * 128 + n];
      if (Wq2) w += Wq2[k * 128 + n];
      s += w * t;
    }
    #pragma unroll
    for (int d = 32; d; d >>= 1) s += __shfl_xor(s, d);
    if (lane == 0) Q[gw] = s;
  }
}

// ---------------- d3: gather_y with in-block B (rows 0..33 from Q) --------------------
// Phase A: per-thread fat-node walk (1 random line/edge, r10 body).
// Phase B: cooperative sB fill from Q (L2-hot), then sync, project, coalesced y write.
__global__ __launch_bounds__(256) void gather_y(
    const int* __restrict__ head_c, const int* __restrict__ head_p,
    const int4* __restrict__ cnm, const int4* __restrict__ cni,
    const float* __restrict__ xc, const float* __restrict__ xp,
    const float* __restrict__ Wcol, const float* __restrict__ bcol,
    const float* __restrict__ Q,
    float* __restrict__ y_c, float* __restrict__ y_p) {
  __shared__ float sB[340];
  int tid = threadIdx.x;
  int i = blockIdx.x * 256 + tid;
  bool active = (i < NCV + NPV);
  bool isC = i < NCV;
  int idx = isC ? i : i - NCV;

  float acc[8] = {0.f, 0.f, 0.f, 0.f, 0.f, 0.f, 0.f, 0.f};
  float cnt = 0.f;
  if (active) {
    const int4* cn = isC ? cnm : cni;
    int e = isC ? head_c[idx] : head_p[idx];
    while (e >= 0) {
      size_t bb = 4 * (size_t)e;
      int4 w0 = cn[bb];
      int4 w1 = cn[bb + 1];
      int4 w2 = cn[bb + 2];
      acc[0] += i2f(w0.y); acc[1] += i2f(w0.z); acc[2] += i2f(w0.w);
      acc[3] += i2f(w1.x); acc[4] += i2f(w1.y); acc[5] += i2f(w1.z); acc[6] += i2f(w1.w);
      acc[7] += i2f(w2.x);
      cnt += 1.f;
      e = w0.x;
    }
  }

  // cooperative B rows 0..33 (all threads participate)
  {
    const float* WcC = Wcol; const float* WcT = Wcol + 128; const float* WcP = Wcol + 256;
    const float* bT = bcol + 128;
    const float* Q1 = Q, *Q2 = Q + 1280, *Q3 = Q + 2560, *Q4 = Q + 3840;
    const float* Q5 = Q + 5120, *Q6 = Q + 6400;
    for (int task = tid; task < 340; task += 256) {
      int r = task / 10, o = task % 10;
      float s = 0.f;
      if (r < 8) {
        for (int j = 0; j < 16; ++j) s += WcT[r * 16 + j] * Q1[(r * 16 + j) * 10 + o];
      } else if (r < 16) {
        int j0 = r - 8;
        for (int j = 0; j < 16; ++j)
          s += WcC[j0 * 16 + j] * (Q2[(j0 * 16 + j) * 10 + o] + Q5[(j0 * 16 + j) * 10 + o]);
      } else if (r == 16) {
        for (int k2 = 0; k2 < 128; ++k2) s += bT[k2] * Q1[k2 * 10 + o];
      } else if (r < 25) {
        int j0 = r - 17;
        for (int j = 0; j < 16; ++j) s += WcT[j0 * 16 + j] * Q3[(j0 * 16 + j) * 10 + o];
      } else if (r < 33) {
        int j0 = r - 25;
        for (int j = 0; j < 16; ++j)
          s += WcP[j0 * 16 + j] * (Q4[(j0 * 16 + j) * 10 + o] + Q6[(j0 * 16 + j) * 10 + o]);
      } else {  // r == 33
        for (int k2 = 0; k2 < 128; ++k2) s += bT[k2] * Q3[k2 * 10 + o];
      }
      sB[task] = 0.5f * s;
    }
  }
  __syncthreads();
  if (!active) return;

  const float* xo = (isC ? xc : xp) + (size_t)idx * 8;
  const float* Bs = sB + (isC ? 0 : 170);
  float gg = cnt > 0.f ? 1.f : 0.f;
  float inv = gg / fmaxf(cnt, 1.f);
  float lg[OUTC];
  #pragma unroll
  for (int o = 0; o < OUTC; ++o) lg[o] = gg * Bs[16 * 10 + o];
  #pragma unroll
  for (int r = 0; r < 8; ++r) {
    float zb = acc[r] * inv;
    float zo = xo[r];
    #pragma unroll
    for (int o = 0; o < OUTC; ++o)
      lg[o] += zb * Bs[r * 10 + o] + zo * Bs[(8 + r) * 10 + o];
  }
  float4* yv = (float4*)((isC ? y_c : y_p) + (size_t)idx * YST);
  yv[0] = make_float4(lg[0], lg[1], lg[2], lg[3]);
  yv[1] = make_float4(lg[4], lg[5], lg[6], lg[7]);
  yv[2] = make_float4(lg[8], lg[9], 0.f, 0.f);
  yv[3] = make_float4(0.f, 0.f, 0.f, 0.f);
}

// ---------------- d4: gather_t with in-block B (rows 34..44 from Q7/T/b_lin) ----------
__global__ __launch_bounds__(256) void gather_t(
    const float* __restrict__ y_c, const float* __restrict__ y_p,
    const float* __restrict__ xt,
    const int* __restrict__ heads_t,
    const int2* __restrict__ tn_m, const int2* __restrict__ tn_i,
    const float* __restrict__ Wcol, const float* __restrict__ bcol,
    const float* __restrict__ b_lin, const float* __restrict__ Wout,
    const float* __restrict__ bout,
    const float* __restrict__ T, const float* __restrict__ Q,
    float* __restrict__ out) {
  __shared__ float sB[110];
  int tid = threadIdx.x;
  {
    const float* WcT = Wcol + 128;
    const float* bC = bcol, *bT = bcol + 128, *bP = bcol + 256;
    const float* Q2 = Q + 1280, *Q4 = Q + 3840, *Q5 = Q + 5120, *Q6 = Q + 6400;
    const float* Q7 = Q + 7680;
    const float* T1 = T, *T2 = T + 1280, *T3 = T + 2560;
    const float* b00 = b_lin, *b01 = b_lin + 128, *b02 = b_lin + 256, *b03 = b_lin + 384;
    const float* b10 = b_lin + 512, *b12 = b_lin + 768;
    for (int task = tid; task < 110; task += 256) {
      int rr = 34 + task / 10, o = task % 10;
      float s = 0.f;
      if (rr < 42) {
        int j0 = rr - 34;
        for (int j = 0; j < 16; ++j) s += WcT[j0 * 16 + j] * Q7[(j0 * 16 + j) * 10 + o];
      } else if (rr == 42) {
        for (int k = 0; k < 128; ++k)
          s += bC[k] * (Q2[k * 10 + o] + Q5[k * 10 + o]) + b01[k] * T1[k * 10 + o];
      } else if (rr == 43) {
        for (int k = 0; k < 128; ++k)
          s += bP[k] * (Q4[k * 10 + o] + Q6[k * 10 + o]) + b03[k] * T2[k * 10 + o];
      } else {  // rr == 44
        for (int n = 0; n < 128; ++n)
          s += (b10[n] + b12[n]) * Wout[n * 10 + o] + bT[n] * Q7[n * 10 + o] +
               (b00[n] + b02[n]) * T3[n * 10 + o];
      }
      float v = 0.5f * s;
      if (rr == 44) v += bout[o];
      sB[task] = v;
    }
  }
  __syncthreads();
  int t = blockIdx.x * 256 + tid;
  if (t >= NTV) return;

  int2 ht = ((const int2*)heads_t)[t];
  int e1 = ht.x, e2 = ht.y;

  float sc[OUTC] = {0.f, 0.f, 0.f, 0.f, 0.f, 0.f, 0.f, 0.f, 0.f, 0.f};
  float sp[OUTC] = {0.f, 0.f, 0.f, 0.f, 0.f, 0.f, 0.f, 0.f, 0.f, 0.f};
  float dc = 0.f, dp = 0.f;
  while (e1 >= 0 || e2 >= 0) {
    if (e1 >= 0) {
      int2 v = tn_m[e1];
      const float* yr = y_c + (size_t)v.y * YST;
      float4 u = *(const float4*)yr;
      float4 w = *(const float4*)(yr + 4);
      float2 z = *(const float2*)(yr + 8);
      sc[0] += u.x; sc[1] += u.y; sc[2] += u.z; sc[3] += u.w;
      sc[4] += w.x; sc[5] += w.y; sc[6] += w.z; sc[7] += w.w;
      sc[8] += z.x; sc[9] += z.y;
      dc += 1.f;
      e1 = v.x;
    }
    if (e2 >= 0) {
      int2 v = tn_i[e2];
      const float* yr = y_p + (size_t)v.y * YST;
      float4 u = *(const float4*)yr;
      float4 w = *(const float4*)(yr + 4);
      float2 z = *(const float2*)(yr + 8);
      sp[0] += u.x; sp[1] += u.y; sp[2] += u.z; sp[3] += u.w;
      sp[4] += w.x; sp[5] += w.y; sp[6] += w.z; sp[7] += w.w;
      sp[8] += z.x; sp[9] += z.y;
      dp += 1.f;
      e2 = v.x;
    }
  }

  float Gc = dc > 0.f ? 1.f : 0.f, Gp = dp > 0.f ? 1.f : 0.f;
  float ivc = 1.f / fmaxf(dc, 1.f), ivp = 1.f / fmaxf(dp, 1.f);

  const float4* xp4 = (const float4*)(xt + (size_t)t * 8);
  float4 xa = xp4[0], xb = xp4[1];
  float xv[8] = {xa.x, xa.y, xa.z, xa.w, xb.x, xb.y, xb.z, xb.w};

  float lg[OUTC];
  #pragma unroll
  for (int o = 0; o < OUTC; ++o)
    lg[o] = sc[o] * ivc + sp[o] * ivp +
            Gc * sB[80 + o] + Gp * sB[90 + o] + sB[100 + o];
  #pragma unroll
  for (int r = 0; r < 8; ++r) {
    float xr = xv[r];
    #pragma unroll
    for (int o = 0; o < OUTC; ++o) lg[o] += xr * sB[r * 10 + o];
  }

  float m = lg[0];
  #pragma unroll
  for (int o = 1; o < OUTC; ++o) m = fmaxf(m, lg[o]);
  float s = 0.f;
  #pragma unroll
  for (int o = 0; o < OUTC; ++o) { lg[o] = __expf(lg[o] - m); s += lg[o]; }
  float invs = 1.0f / s;
  float* op = &out[(size_t)t * OUTC];
  #pragma unroll
  for (int o = 0; o < 5; ++o) {
    float2 p2; p2.x = lg[2 * o] * invs; p2.y = lg[2 * o + 1] * invs;
    *(float2*)&op[2 * o] = p2;
  }
}

extern "C" void kernel_launch(void* const* d_in, const int* in_sizes, int n_in,
                              void* d_out, int out_size, void* d_ws, size_t ws_size,
                              hipStream_t stream) {
  const float* x_c   = (const float*)d_in[0];
  const float* x_t   = (const float*)d_in[1];
  const float* x_p   = (const float*)d_in[2];
  const float* W_col = (const float*)d_in[3];
  const float* b_col = (const float*)d_in[4];
  const float* Wn    = (const float*)d_in[5];
  const float* Wr    = (const float*)d_in[6];
  const float* b_lin = (const float*)d_in[7];
  const float* W_out = (const float*)d_in[8];
  const float* b_out = (const float*)d_in[9];
  const int* e_m_src = (const int*)d_in[10];
  const int* e_m_dst = (const int*)d_in[11];
  const int* e_i_src = (const int*)d_in[12];
  const int* e_i_dst = (const int*)d_in[13];
  float* out = (float*)d_out;

  // ---- workspace carve-out (~78 MB; ws_size = 256 MiB) ----
  size_t cursor = 0;
  char* base = (char*)d_ws;
  auto alloc = [&](size_t bytes) {
    void* p = base + cursor;
    cursor += (bytes + 255) & ~(size_t)255;
    return p;
  };
  int* heads   = (int*)alloc((size_t)NHEADS * 4);                  // 3.0 MB
  int* head_c  = heads;
  int* head_p  = heads + NCV;
  int* heads_t = heads + NCV + NPV;                                // int2-interleaved per t
  int4* cnm = (int4*)alloc((size_t)EMV * 64);                      // 19.2 MB (fat)
  int4* cni = (int4*)alloc((size_t)EIV * 64);                      // 38.4 MB (fat)
  int2* tn_m = (int2*)alloc((size_t)EMV * 8);                      // 2.4 MB
  int2* tn_i = (int2*)alloc((size_t)EIV * 8);                      // 4.8 MB
  float* y_c = (float*)alloc((size_t)NCV * YST * 4);               // 6.4 MB
  float* y_p = (float*)alloc((size_t)NPV * YST * 4);               // 3.2 MB
  float* T   = (float*)alloc(3 * 1280 * 4);
  float* Q   = (float*)alloc(7 * 1280 * 4);

  // ---- d1: heads init to -1 ----
  hipMemsetAsync(heads, 0xFF, (size_t)NHEADS * 4, stream);

  // ---- d2: build (both sides, in-thread MLP) + prepT tail + prepQ-direct tail ----
  build_mega<<<NEB + PTB + NQB, 256, 0, stream>>>(
      e_m_src, e_m_dst, e_i_src, e_i_dst, x_t,
      head_c, head_p, heads_t, cnm, cni, tn_m, tn_i,
      Wn, Wr, W_out, T, Q);

  // ---- d3: gather_y (walk fat c/p lists + in-block B rows 0..33) ----
  gather_y<<<GYB, 256, 0, stream>>>(
      head_c, head_p, cnm, cni, x_c, x_p, W_col, b_col, Q, y_c, y_p);

  // ---- d4: gather_t (in-block B rows 34..44 + dual thin walks + softmax) ----
  gather_t<<<(NTV + 255) / 256, 256, 0, stream>>>(
      y_c, y_p, x_t, heads_t, tn_m, tn_i,
      W_col, b_col, b_lin, W_out, b_out, T, Q, out);
}

// Round 13
// 264.768 us; speedup vs baseline: 1.4744x; 1.4744x over previous
//
#include <hip/hip_runtime.h>

#define NCV 100000
#define NTV 300000
#define NPV 50000
#define DD 128
#define OUTC 10
#define EMV 300000
#define EIV 600000
#define YST 16
#define NHEADS (NCV + NPV + 2 * NTV)
#define HIB ((NHEADS + 255) / 256)       // heads-init blocks
#define PTB ((3 * 1280 * 64) / 256)      // prepT blocks (wave-per-output)
#define NEB ((EIV + 255) / 256)          // edge blocks
#define QB  ((7 * 1280 * 64) / 256)      // prepQ blocks (wave-per-output)
#define GYB ((NCV + NPV + 255) / 256)    // gather_y blocks

__device__ __forceinline__ float i2f(int v) { return __int_as_float(v); }

// ---------------- d1: heads init (blocks 0..HIB) + prepT (tail blocks) ----------------
// Both branches are ~16 VGPR; no cross-branch dependency.
__global__ __launch_bounds__(256) void init_prepT(
    int* __restrict__ heads,
    const float* __restrict__ Wn10, const float* __restrict__ Wn12,
    const float* __restrict__ Wr10, const float* __restrict__ Wr12,
    const float* __restrict__ Wout, float* __restrict__ T) {
  int b = blockIdx.x;
  int tid = threadIdx.x;
  if (b < HIB) {
    int i = b * 256 + tid;
    if (i < NHEADS) heads[i] = -1;
    return;
  }
  // prepT: wave-per-output (verbatim r10)
  int gw = ((b - HIB) * 256 + tid) >> 6;
  int lane = tid & 63;
  if (gw >= 3 * 1280) return;
  int mat = gw / 1280, r = gw % 1280, n = r / 10, o = r % 10;
  float s = 0.f;
  #pragma unroll
  for (int mi = 0; mi < 2; ++mi) {
    int m = lane + mi * 64;
    float w;
    if (mat == 0) w = Wn10[n * 128 + m];
    else if (mat == 1) w = Wn12[n * 128 + m];
    else w = 0.5f * (Wr10[n * 128 + m] + Wr12[n * 128 + m]);
    s += w * Wout[m * 10 + o];
  }
  #pragma unroll
  for (int d = 32; d; d >>= 1) s += __shfl_xor(s, d);
  if (lane == 0) T[gw] = s;
}

// ---------------- d2: build (r10 body, blocks 0..NEB) + light prepQ (tail) ------------
// Build: both-side exchs in-thread (MLP-overlapped), fat 48B c/p-nodes
//   {next,xt0..2}{xt3..6}{xt7,0,0,0}, thin int2 t-nodes {next,src}. 82us @ 72% occ (r10).
// prepQ tail: r8's wave-per-output body reading T (completed in d1). Low VGPR, no LDS —
//   keeps the unified register allocation small so build occupancy is preserved (r12 lesson).
__global__ __launch_bounds__(256) void build_prepQ(
    const int* __restrict__ ems, const int* __restrict__ emd,
    const int* __restrict__ eis, const int* __restrict__ eid,
    const float* __restrict__ xt,
    int* __restrict__ head_c, int* __restrict__ head_p,
    int* __restrict__ heads_t,
    int4* __restrict__ cnm, int4* __restrict__ cni,
    int2* __restrict__ tn_m, int2* __restrict__ tn_i,
    const float* __restrict__ Wn01, const float* __restrict__ Wr01,
    const float* __restrict__ Wn03, const float* __restrict__ Wr03,
    const float* __restrict__ Wn00, const float* __restrict__ Wn02,
    const float* __restrict__ Wr00, const float* __restrict__ Wr02,
    const float* __restrict__ T, float* __restrict__ Q) {
  int b = blockIdx.x;
  int tid = threadIdx.x;
  if (b < NEB) {
    int e = b * 256 + tid;
    if (e < EMV) {
      int c = ems[e], t = emd[e];
      int cn = atomicExch(&head_c[c], e);
      int tn = atomicExch(&heads_t[2 * t], e);
      const int4* xr = (const int4*)(xt + (size_t)t * 8);
      int4 x0 = xr[0], x1 = xr[1];
      size_t bb = 4 * (size_t)e;
      cnm[bb]     = make_int4(cn, x0.x, x0.y, x0.z);
      cnm[bb + 1] = make_int4(x0.w, x1.x, x1.y, x1.z);
      cnm[bb + 2] = make_int4(x1.w, 0, 0, 0);
      tn_m[e] = make_int2(tn, c);
    }
    if (e < EIV) {
      int p = eis[e], t = eid[e];
      int pn = atomicExch(&head_p[p], e);
      int tn = atomicExch(&heads_t[2 * t + 1], e);
      const int4* xr = (const int4*)(xt + (size_t)t * 8);
      int4 x0 = xr[0], x1 = xr[1];
      size_t bb = 4 * (size_t)e;
      cni[bb]     = make_int4(pn, x0.x, x0.y, x0.z);
      cni[bb + 1] = make_int4(x0.w, x1.x, x1.y, x1.z);
      cni[bb + 2] = make_int4(x1.w, 0, 0, 0);
      tn_i[e] = make_int2(tn, p);
    }
    return;
  }

  // prepQ: wave-per-output (verbatim r8 body; reads T from d1)
  int gw = ((b - NEB) * 256 + tid) >> 6;
  int lane = tid & 63;
  if (gw >= 7 * 1280) return;
  int q = gw / 1280, r = gw % 1280, k = r / 10, o = r % 10;
  const float* T1 = T, *T2 = T + 1280, *T3 = T + 2560;
  float s = 0.f;
  #pragma unroll
  for (int ni = 0; ni < 2; ++ni) {
    int n = lane + ni * 64;
    float w, t;
    switch (q) {
      case 0: w = Wn01[k * 128 + n]; t = T1[n * 10 + o]; break;
      case 1: w = Wr01[k * 128 + n]; t = T1[n * 10 + o]; break;
      case 2: w = Wn03[k * 128 + n]; t = T2[n * 10 + o]; break;
      case 3: w = Wr03[k * 128 + n]; t = T2[n * 10 + o]; break;
      case 4: w = Wn00[k * 128 + n]; t = T3[n * 10 + o]; break;
      case 5: w = Wn02[k * 128 + n]; t = T3[n * 10 + o]; break;
      default: w = Wr00[k * 128 + n] + Wr02[k * 128 + n]; t = T3[n * 10 + o]; break;
    }
    s += w * t;
  }
  #pragma unroll
  for (int d = 32; d; d >>= 1) s += __shfl_xor(s, d);
  if (lane == 0) Q[gw] = s;
}

// ---------------- d3: gather_y with in-block B rows 0..33 (verbatim r12) --------------
__global__ __launch_bounds__(256) void gather_y(
    const int* __restrict__ head_c, const int* __restrict__ head_p,
    const int4* __restrict__ cnm, const int4* __restrict__ cni,
    const float* __restrict__ xc, const float* __restrict__ xp,
    const float* __restrict__ Wcol, const float* __restrict__ bcol,
    const float* __restrict__ Q,
    float* __restrict__ y_c, float* __restrict__ y_p) {
  __shared__ float sB[340];
  int tid = threadIdx.x;
  int i = blockIdx.x * 256 + tid;
  bool active = (i < NCV + NPV);
  bool isC = i < NCV;
  int idx = isC ? i : i - NCV;

  float acc[8] = {0.f, 0.f, 0.f, 0.f, 0.f, 0.f, 0.f, 0.f};
  float cnt = 0.f;
  if (active) {
    const int4* cn = isC ? cnm : cni;
    int e = isC ? head_c[idx] : head_p[idx];
    while (e >= 0) {
      size_t bb = 4 * (size_t)e;
      int4 w0 = cn[bb];
      int4 w1 = cn[bb + 1];
      int4 w2 = cn[bb + 2];
      acc[0] += i2f(w0.y); acc[1] += i2f(w0.z); acc[2] += i2f(w0.w);
      acc[3] += i2f(w1.x); acc[4] += i2f(w1.y); acc[5] += i2f(w1.z); acc[6] += i2f(w1.w);
      acc[7] += i2f(w2.x);
      cnt += 1.f;
      e = w0.x;
    }
  }

  // cooperative B rows 0..33 (all threads participate; Q is L2-hot)
  {
    const float* WcC = Wcol; const float* WcT = Wcol + 128; const float* WcP = Wcol + 256;
    const float* bT = bcol + 128;
    const float* Q1 = Q, *Q2 = Q + 1280, *Q3 = Q + 2560, *Q4 = Q + 3840;
    const float* Q5 = Q + 5120, *Q6 = Q + 6400;
    for (int task = tid; task < 340; task += 256) {
      int r = task / 10, o = task % 10;
      float s = 0.f;
      if (r < 8) {
        for (int j = 0; j < 16; ++j) s += WcT[r * 16 + j] * Q1[(r * 16 + j) * 10 + o];
      } else if (r < 16) {
        int j0 = r - 8;
        for (int j = 0; j < 16; ++j)
          s += WcC[j0 * 16 + j] * (Q2[(j0 * 16 + j) * 10 + o] + Q5[(j0 * 16 + j) * 10 + o]);
      } else if (r == 16) {
        for (int k2 = 0; k2 < 128; ++k2) s += bT[k2] * Q1[k2 * 10 + o];
      } else if (r < 25) {
        int j0 = r - 17;
        for (int j = 0; j < 16; ++j) s += WcT[j0 * 16 + j] * Q3[(j0 * 16 + j) * 10 + o];
      } else if (r < 33) {
        int j0 = r - 25;
        for (int j = 0; j < 16; ++j)
          s += WcP[j0 * 16 + j] * (Q4[(j0 * 16 + j) * 10 + o] + Q6[(j0 * 16 + j) * 10 + o]);
      } else {  // r == 33
        for (int k2 = 0; k2 < 128; ++k2) s += bT[k2] * Q3[k2 * 10 + o];
      }
      sB[task] = 0.5f * s;
    }
  }
  __syncthreads();
  if (!active) return;

  const float* xo = (isC ? xc : xp) + (size_t)idx * 8;
  const float* Bs = sB + (isC ? 0 : 170);
  float gg = cnt > 0.f ? 1.f : 0.f;
  float inv = gg / fmaxf(cnt, 1.f);
  float lg[OUTC];
  #pragma unroll
  for (int o = 0; o < OUTC; ++o) lg[o] = gg * Bs[16 * 10 + o];
  #pragma unroll
  for (int r = 0; r < 8; ++r) {
    float zb = acc[r] * inv;
    float zo = xo[r];
    #pragma unroll
    for (int o = 0; o < OUTC; ++o)
      lg[o] += zb * Bs[r * 10 + o] + zo * Bs[(8 + r) * 10 + o];
  }
  float4* yv = (float4*)((isC ? y_c : y_p) + (size_t)idx * YST);
  yv[0] = make_float4(lg[0], lg[1], lg[2], lg[3]);
  yv[1] = make_float4(lg[4], lg[5], lg[6], lg[7]);
  yv[2] = make_float4(lg[8], lg[9], 0.f, 0.f);
  yv[3] = make_float4(0.f, 0.f, 0.f, 0.f);
}

// ---------------- d4: gather_t with in-block B rows 34..44 (verbatim r12) -------------
__global__ __launch_bounds__(256) void gather_t(
    const float* __restrict__ y_c, const float* __restrict__ y_p,
    const float* __restrict__ xt,
    const int* __restrict__ heads_t,
    const int2* __restrict__ tn_m, const int2* __restrict__ tn_i,
    const float* __restrict__ Wcol, const float* __restrict__ bcol,
    const float* __restrict__ b_lin, const float* __restrict__ Wout,
    const float* __restrict__ bout,
    const float* __restrict__ T, const float* __restrict__ Q,
    float* __restrict__ out) {
  __shared__ float sB[110];
  int tid = threadIdx.x;
  {
    const float* WcT = Wcol + 128;
    const float* bC = bcol, *bT = bcol + 128, *bP = bcol + 256;
    const float* Q2 = Q + 1280, *Q4 = Q + 3840, *Q5 = Q + 5120, *Q6 = Q + 6400;
    const float* Q7 = Q + 7680;
    const float* T1 = T, *T2 = T + 1280, *T3 = T + 2560;
    const float* b00 = b_lin, *b01 = b_lin + 128, *b02 = b_lin + 256, *b03 = b_lin + 384;
    const float* b10 = b_lin + 512, *b12 = b_lin + 768;
    for (int task = tid; task < 110; task += 256) {
      int rr = 34 + task / 10, o = task % 10;
      float s = 0.f;
      if (rr < 42) {
        int j0 = rr - 34;
        for (int j = 0; j < 16; ++j) s += WcT[j0 * 16 + j] * Q7[(j0 * 16 + j) * 10 + o];
      } else if (rr == 42) {
        for (int k = 0; k < 128; ++k)
          s += bC[k] * (Q2[k * 10 + o] + Q5[k * 10 + o]) + b01[k] * T1[k * 10 + o];
      } else if (rr == 43) {
        for (int k = 0; k < 128; ++k)
          s += bP[k] * (Q4[k * 10 + o] + Q6[k * 10 + o]) + b03[k] * T2[k * 10 + o];
      } else {  // rr == 44
        for (int n = 0; n < 128; ++n)
          s += (b10[n] + b12[n]) * Wout[n * 10 + o] + bT[n] * Q7[n * 10 + o] +
               (b00[n] + b02[n]) * T3[n * 10 + o];
      }
      float v = 0.5f * s;
      if (rr == 44) v += bout[o];
      sB[task] = v;
    }
  }
  __syncthreads();
  int t = blockIdx.x * 256 + tid;
  if (t >= NTV) return;

  int2 ht = ((const int2*)heads_t)[t];
  int e1 = ht.x, e2 = ht.y;

  float sc[OUTC] = {0.f, 0.f, 0.f, 0.f, 0.f, 0.f, 0.f, 0.f, 0.f, 0.f};
  float sp[OUTC] = {0.f, 0.f, 0.f, 0.f, 0.f, 0.f, 0.f, 0.f, 0.f, 0.f};
  float dc = 0.f, dp = 0.f;
  while (e1 >= 0 || e2 >= 0) {
    if (e1 >= 0) {
      int2 v = tn_m[e1];
      const float* yr = y_c + (size_t)v.y * YST;
      float4 u = *(const float4*)yr;
      float4 w = *(const float4*)(yr + 4);
      float2 z = *(const float2*)(yr + 8);
      sc[0] += u.x; sc[1] += u.y; sc[2] += u.z; sc[3] += u.w;
      sc[4] += w.x; sc[5] += w.y; sc[6] += w.z; sc[7] += w.w;
      sc[8] += z.x; sc[9] += z.y;
      dc += 1.f;
      e1 = v.x;
    }
    if (e2 >= 0) {
      int2 v = tn_i[e2];
      const float* yr = y_p + (size_t)v.y * YST;
      float4 u = *(const float4*)yr;
      float4 w = *(const float4*)(yr + 4);
      float2 z = *(const float2*)(yr + 8);
      sp[0] += u.x; sp[1] += u.y; sp[2] += u.z; sp[3] += u.w;
      sp[4] += w.x; sp[5] += w.y; sp[6] += w.z; sp[7] += w.w;
      sp[8] += z.x; sp[9] += z.y;
      dp += 1.f;
      e2 = v.x;
    }
  }

  float Gc = dc > 0.f ? 1.f : 0.f, Gp = dp > 0.f ? 1.f : 0.f;
  float ivc = 1.f / fmaxf(dc, 1.f), ivp = 1.f / fmaxf(dp, 1.f);

  const float4* xp4 = (const float4*)(xt + (size_t)t * 8);
  float4 xa = xp4[0], xb = xp4[1];
  float xv[8] = {xa.x, xa.y, xa.z, xa.w, xb.x, xb.y, xb.z, xb.w};

  float lg[OUTC];
  #pragma unroll
  for (int o = 0; o < OUTC; ++o)
    lg[o] = sc[o] * ivc + sp[o] * ivp +
            Gc * sB[80 + o] + Gp * sB[90 + o] + sB[100 + o];
  #pragma unroll
  for (int r = 0; r < 8; ++r) {
    float xr = xv[r];
    #pragma unroll
    for (int o = 0; o < OUTC; ++o) lg[o] += xr * sB[r * 10 + o];
  }

  float m = lg[0];
  #pragma unroll
  for (int o = 1; o < OUTC; ++o) m = fmaxf(m, lg[o]);
  float s = 0.f;
  #pragma unroll
  for (int o = 0; o < OUTC; ++o) { lg[o] = __expf(lg[o] - m); s += lg[o]; }
  float invs = 1.0f / s;
  float* op = &out[(size_t)t * OUTC];
  #pragma unroll
  for (int o = 0; o < 5; ++o) {
    float2 p2; p2.x = lg[2 * o] * invs; p2.y = lg[2 * o + 1] * invs;
    *(float2*)&op[2 * o] = p2;
  }
}

extern "C" void kernel_launch(void* const* d_in, const int* in_sizes, int n_in,
                              void* d_out, int out_size, void* d_ws, size_t ws_size,
                              hipStream_t stream) {
  const float* x_c   = (const float*)d_in[0];
  const float* x_t   = (const float*)d_in[1];
  const float* x_p   = (const float*)d_in[2];
  const float* W_col = (const float*)d_in[3];
  const float* b_col = (const float*)d_in[4];
  const float* Wn    = (const float*)d_in[5];
  const float* Wr    = (const float*)d_in[6];
  const float* b_lin = (const float*)d_in[7];
  const float* W_out = (const float*)d_in[8];
  const float* b_out = (const float*)d_in[9];
  const int* e_m_src = (const int*)d_in[10];
  const int* e_m_dst = (const int*)d_in[11];
  const int* e_i_src = (const int*)d_in[12];
  const int* e_i_dst = (const int*)d_in[13];
  float* out = (float*)d_out;

  // ---- workspace carve-out (~78 MB; ws_size = 256 MiB) ----
  size_t cursor = 0;
  char* base = (char*)d_ws;
  auto alloc = [&](size_t bytes) {
    void* p = base + cursor;
    cursor += (bytes + 255) & ~(size_t)255;
    return p;
  };
  int* heads   = (int*)alloc((size_t)NHEADS * 4);                  // 3.0 MB
  int* head_c  = heads;
  int* head_p  = heads + NCV;
  int* heads_t = heads + NCV + NPV;                                // int2-interleaved per t
  int4* cnm = (int4*)alloc((size_t)EMV * 64);                      // 19.2 MB (fat)
  int4* cni = (int4*)alloc((size_t)EIV * 64);                      // 38.4 MB (fat)
  int2* tn_m = (int2*)alloc((size_t)EMV * 8);                      // 2.4 MB
  int2* tn_i = (int2*)alloc((size_t)EIV * 8);                      // 4.8 MB
  float* y_c = (float*)alloc((size_t)NCV * YST * 4);               // 6.4 MB
  float* y_p = (float*)alloc((size_t)NPV * YST * 4);               // 3.2 MB
  float* T   = (float*)alloc(3 * 1280 * 4);
  float* Q   = (float*)alloc(7 * 1280 * 4);

  const float* Wn_l[2][4]; const float* Wr_l[2][4];
  for (int l = 0; l < 2; ++l)
    for (int r = 0; r < 4; ++r) {
      Wn_l[l][r] = Wn + (size_t)(l * 4 + r) * DD * DD;
      Wr_l[l][r] = Wr + (size_t)(l * 4 + r) * DD * DD;
    }

  // ---- d1: heads init + prepT (independent light work, one dispatch) ----
  init_prepT<<<HIB + PTB, 256, 0, stream>>>(
      heads, Wn_l[1][0], Wn_l[1][2], Wr_l[1][0], Wr_l[1][2], W_out, T);

  // ---- d2: build (both sides in-thread, fat c/p + thin t nodes) + light prepQ tail ----
  build_prepQ<<<NEB + QB, 256, 0, stream>>>(
      e_m_src, e_m_dst, e_i_src, e_i_dst, x_t,
      head_c, head_p, heads_t, cnm, cni, tn_m, tn_i,
      Wn_l[0][1], Wr_l[0][1], Wn_l[0][3], Wr_l[0][3],
      Wn_l[0][0], Wn_l[0][2], Wr_l[0][0], Wr_l[0][2], T, Q);

  // ---- d3: gather_y (walk fat c/p lists + in-block B rows 0..33) ----
  gather_y<<<GYB, 256, 0, stream>>>(
      head_c, head_p, cnm, cni, x_c, x_p, W_col, b_col, Q, y_c, y_p);

  // ---- d4: gather_t (in-block B rows 34..44 + dual thin walks + softmax) ----
  gather_t<<<(NTV + 255) / 256, 256, 0, stream>>>(
      y_c, y_p, x_t, heads_t, tn_m, tn_i,
      W_col, b_col, b_lin, W_out, b_out, T, Q, out);
}

// Round 14
// 223.830 us; speedup vs baseline: 1.7440x; 1.1829x over previous
//
#include <hip/hip_runtime.h>

#define NCV 100000
#define NTV 300000
#define NPV 50000
#define DD 128
#define OUTC 10
#define EMV 300000
#define EIV 600000
#define YST 16
#define NHEADS (NCV + NPV + 2 * NTV)
#define HIB ((NHEADS + 255) / 256)       // heads-init blocks
#define PTB ((3 * 1280 * 64) / 256)      // prepT blocks (wave-per-output)
#define NEB ((EIV + 255) / 256)          // edge blocks
#define QB  ((7 * 1280 * 64) / 256)      // prepQ blocks (wave-per-output)
#define GYB ((NCV + NPV + 255) / 256)    // gather_y blocks

__device__ __forceinline__ float i2f(int v) { return __int_as_float(v); }

// ---------------- d1: heads init (blocks 0..HIB) + prepT (tail blocks) ----------------
__global__ __launch_bounds__(256) void init_prepT(
    int* __restrict__ heads,
    const float* __restrict__ Wn10, const float* __restrict__ Wn12,
    const float* __restrict__ Wr10, const float* __restrict__ Wr12,
    const float* __restrict__ Wout, float* __restrict__ T) {
  int b = blockIdx.x;
  int tid = threadIdx.x;
  if (b < HIB) {
    int i = b * 256 + tid;
    if (i < NHEADS) heads[i] = -1;
    return;
  }
  int gw = ((b - HIB) * 256 + tid) >> 6;
  int lane = tid & 63;
  if (gw >= 3 * 1280) return;
  int mat = gw / 1280, r = gw % 1280, n = r / 10, o = r % 10;
  float s = 0.f;
  #pragma unroll
  for (int mi = 0; mi < 2; ++mi) {
    int m = lane + mi * 64;
    float w;
    if (mat == 0) w = Wn10[n * 128 + m];
    else if (mat == 1) w = Wn12[n * 128 + m];
    else w = 0.5f * (Wr10[n * 128 + m] + Wr12[n * 128 + m]);
    s += w * Wout[m * 10 + o];
  }
  #pragma unroll
  for (int d = 32; d; d >>= 1) s += __shfl_xor(s, d);
  if (lane == 0) T[gw] = s;
}

// ---------------- d2: build (r10 body) + light prepQ tail (r13-verified, VGPR 16) -----
__global__ __launch_bounds__(256) void build_prepQ(
    const int* __restrict__ ems, const int* __restrict__ emd,
    const int* __restrict__ eis, const int* __restrict__ eid,
    const float* __restrict__ xt,
    int* __restrict__ head_c, int* __restrict__ head_p,
    int* __restrict__ heads_t,
    int4* __restrict__ cnm, int4* __restrict__ cni,
    int2* __restrict__ tn_m, int2* __restrict__ tn_i,
    const float* __restrict__ Wn01, const float* __restrict__ Wr01,
    const float* __restrict__ Wn03, const float* __restrict__ Wr03,
    const float* __restrict__ Wn00, const float* __restrict__ Wn02,
    const float* __restrict__ Wr00, const float* __restrict__ Wr02,
    const float* __restrict__ T, float* __restrict__ Q) {
  int b = blockIdx.x;
  int tid = threadIdx.x;
  if (b < NEB) {
    int e = b * 256 + tid;
    if (e < EMV) {
      int c = ems[e], t = emd[e];
      int cn = atomicExch(&head_c[c], e);
      int tn = atomicExch(&heads_t[2 * t], e);
      const int4* xr = (const int4*)(xt + (size_t)t * 8);
      int4 x0 = xr[0], x1 = xr[1];
      size_t bb = 4 * (size_t)e;
      cnm[bb]     = make_int4(cn, x0.x, x0.y, x0.z);
      cnm[bb + 1] = make_int4(x0.w, x1.x, x1.y, x1.z);
      cnm[bb + 2] = make_int4(x1.w, 0, 0, 0);
      tn_m[e] = make_int2(tn, c);
    }
    if (e < EIV) {
      int p = eis[e], t = eid[e];
      int pn = atomicExch(&head_p[p], e);
      int tn = atomicExch(&heads_t[2 * t + 1], e);
      const int4* xr = (const int4*)(xt + (size_t)t * 8);
      int4 x0 = xr[0], x1 = xr[1];
      size_t bb = 4 * (size_t)e;
      cni[bb]     = make_int4(pn, x0.x, x0.y, x0.z);
      cni[bb + 1] = make_int4(x0.w, x1.x, x1.y, x1.z);
      cni[bb + 2] = make_int4(x1.w, 0, 0, 0);
      tn_i[e] = make_int2(tn, p);
    }
    return;
  }

  // prepQ: wave-per-output (verbatim r8 body; reads T from d1)
  int gw = ((b - NEB) * 256 + tid) >> 6;
  int lane = tid & 63;
  if (gw >= 7 * 1280) return;
  int q = gw / 1280, r = gw % 1280, k = r / 10, o = r % 10;
  const float* T1 = T, *T2 = T + 1280, *T3 = T + 2560;
  float s = 0.f;
  #pragma unroll
  for (int ni = 0; ni < 2; ++ni) {
    int n = lane + ni * 64;
    float w, t;
    switch (q) {
      case 0: w = Wn01[k * 128 + n]; t = T1[n * 10 + o]; break;
      case 1: w = Wr01[k * 128 + n]; t = T1[n * 10 + o]; break;
      case 2: w = Wn03[k * 128 + n]; t = T2[n * 10 + o]; break;
      case 3: w = Wr03[k * 128 + n]; t = T2[n * 10 + o]; break;
      case 4: w = Wn00[k * 128 + n]; t = T3[n * 10 + o]; break;
      case 5: w = Wn02[k * 128 + n]; t = T3[n * 10 + o]; break;
      default: w = Wr00[k * 128 + n] + Wr02[k * 128 + n]; t = T3[n * 10 + o]; break;
    }
    s += w * t;
  }
  #pragma unroll
  for (int d = 32; d; d >>= 1) s += __shfl_xor(s, d);
  if (lane == 0) Q[gw] = s;
}

// ---------------- d3: prepB (verbatim r8, wave-per-output) ----------------------------
__global__ __launch_bounds__(256) void prep_B_w(
    const float* __restrict__ Wcol, const float* __restrict__ bcol,
    const float* __restrict__ b_lin, const float* __restrict__ Wout,
    const float* __restrict__ bout, const float* __restrict__ T,
    const float* __restrict__ Q, float* __restrict__ B) {
  int gw = (blockIdx.x * 256 + threadIdx.x) >> 6;
  int lane = threadIdx.x & 63;
  if (gw >= 450) return;
  int r = gw / 10, o = gw % 10;
  const float* WcC = Wcol, *WcT = Wcol + 128, *WcP = Wcol + 256;
  const float* bC = bcol, *bT = bcol + 128, *bP = bcol + 256;
  const float* Q1 = Q, *Q2 = Q + 1280, *Q3 = Q + 2560, *Q4 = Q + 3840;
  const float* Q5 = Q + 5120, *Q6 = Q + 6400, *Q7 = Q + 7680;
  const float* T1 = T, *T2 = T + 1280, *T3 = T + 2560;
  const float* b00 = b_lin, *b01 = b_lin + 128, *b02 = b_lin + 256, *b03 = b_lin + 384;
  const float* b10 = b_lin + 512, *b12 = b_lin + 768;
  float s = 0.f;
  if (r < 8) {
    if (lane < 16) s = WcT[r * 16 + lane] * Q1[(r * 16 + lane) * 10 + o];
  } else if (r < 16) {
    int j = r - 8;
    if (lane < 16)
      s = WcC[j * 16 + lane] * (Q2[(j * 16 + lane) * 10 + o] + Q5[(j * 16 + lane) * 10 + o]);
  } else if (r == 16) {
    for (int k2 = lane; k2 < 128; k2 += 64) s += bT[k2] * Q1[k2 * 10 + o];
  } else if (r < 25) {
    int j = r - 17;
    if (lane < 16) s = WcT[j * 16 + lane] * Q3[(j * 16 + lane) * 10 + o];
  } else if (r < 33) {
    int j = r - 25;
    if (lane < 16)
      s = WcP[j * 16 + lane] * (Q4[(j * 16 + lane) * 10 + o] + Q6[(j * 16 + lane) * 10 + o]);
  } else if (r == 33) {
    for (int k2 = lane; k2 < 128; k2 += 64) s += bT[k2] * Q3[k2 * 10 + o];
  } else if (r < 42) {
    int j = r - 34;
    if (lane < 16) s = WcT[j * 16 + lane] * Q7[(j * 16 + lane) * 10 + o];
  } else if (r == 42) {
    for (int k2 = lane; k2 < 128; k2 += 64)
      s += bC[k2] * (Q2[k2 * 10 + o] + Q5[k2 * 10 + o]) + b01[k2] * T1[k2 * 10 + o];
  } else if (r == 43) {
    for (int k2 = lane; k2 < 128; k2 += 64)
      s += bP[k2] * (Q4[k2 * 10 + o] + Q6[k2 * 10 + o]) + b03[k2] * T2[k2 * 10 + o];
  } else {
    for (int n = lane; n < 128; n += 64)
      s += (b10[n] + b12[n]) * Wout[n * 10 + o] + bT[n] * Q7[n * 10 + o] +
           (b00[n] + b02[n]) * T3[n * 10 + o];
  }
  #pragma unroll
  for (int d = 32; d; d >>= 1) s += __shfl_xor(s, d);
  if (lane == 0) {
    float v = s * 0.5f;
    if (r == 44) v += bout[o];
    B[gw] = v;
  }
}

// ---------------- d4: gather_y (verbatim r10 — fat-node walk, global B -> LDS) --------
__global__ __launch_bounds__(256) void gather_y(
    const int* __restrict__ head_c, const int* __restrict__ head_p,
    const int4* __restrict__ cnm, const int4* __restrict__ cni,
    const float* __restrict__ xc, const float* __restrict__ xp,
    const float* __restrict__ B,
    float* __restrict__ y_c, float* __restrict__ y_p) {
  __shared__ float sB[340];
  int tid = threadIdx.x;
  for (int i = tid; i < 340; i += 256) sB[i] = B[i];
  __syncthreads();
  int i = blockIdx.x * 256 + tid;
  if (i >= NCV + NPV) return;
  bool isC = i < NCV;
  int idx = isC ? i : i - NCV;
  const int4* cn = isC ? cnm : cni;
  int e = isC ? head_c[idx] : head_p[idx];

  float acc[8] = {0.f, 0.f, 0.f, 0.f, 0.f, 0.f, 0.f, 0.f};
  float cnt = 0.f;
  while (e >= 0) {
    size_t bb = 4 * (size_t)e;
    int4 w0 = cn[bb];
    int4 w1 = cn[bb + 1];
    int4 w2 = cn[bb + 2];
    acc[0] += i2f(w0.y); acc[1] += i2f(w0.z); acc[2] += i2f(w0.w);
    acc[3] += i2f(w1.x); acc[4] += i2f(w1.y); acc[5] += i2f(w1.z); acc[6] += i2f(w1.w);
    acc[7] += i2f(w2.x);
    cnt += 1.f;
    e = w0.x;
  }

  const float* xo = (isC ? xc : xp) + (size_t)idx * 8;
  const float* Bs = sB + (isC ? 0 : 170);
  float gg = cnt > 0.f ? 1.f : 0.f;
  float inv = gg / fmaxf(cnt, 1.f);
  float lg[OUTC];
  #pragma unroll
  for (int o = 0; o < OUTC; ++o) lg[o] = gg * Bs[16 * 10 + o];
  #pragma unroll
  for (int r = 0; r < 8; ++r) {
    float zb = acc[r] * inv;
    float zo = xo[r];
    #pragma unroll
    for (int o = 0; o < OUTC; ++o)
      lg[o] += zb * Bs[r * 10 + o] + zo * Bs[(8 + r) * 10 + o];
  }
  float4* yv = (float4*)((isC ? y_c : y_p) + (size_t)idx * YST);
  yv[0] = make_float4(lg[0], lg[1], lg[2], lg[3]);
  yv[1] = make_float4(lg[4], lg[5], lg[6], lg[7]);
  yv[2] = make_float4(lg[8], lg[9], 0.f, 0.f);
  yv[3] = make_float4(0.f, 0.f, 0.f, 0.f);
}

// ---------------- d5: gather_t (verbatim r10 — dual thin walk, global B -> LDS) -------
__global__ __launch_bounds__(256) void gather_t(
    const float* __restrict__ y_c, const float* __restrict__ y_p,
    const float* __restrict__ xt,
    const int* __restrict__ heads_t,
    const int2* __restrict__ tn_m, const int2* __restrict__ tn_i,
    const float* __restrict__ B, float* __restrict__ out) {
  __shared__ float sB[110];
  int tid = threadIdx.x;
  for (int i = tid; i < 110; i += 256) sB[i] = B[340 + i];
  __syncthreads();
  int t = blockIdx.x * 256 + tid;
  if (t >= NTV) return;

  int2 ht = ((const int2*)heads_t)[t];
  int e1 = ht.x, e2 = ht.y;

  float sc[OUTC] = {0.f, 0.f, 0.f, 0.f, 0.f, 0.f, 0.f, 0.f, 0.f, 0.f};
  float sp[OUTC] = {0.f, 0.f, 0.f, 0.f, 0.f, 0.f, 0.f, 0.f, 0.f, 0.f};
  float dc = 0.f, dp = 0.f;
  while (e1 >= 0 || e2 >= 0) {
    if (e1 >= 0) {
      int2 v = tn_m[e1];
      const float* yr = y_c + (size_t)v.y * YST;
      float4 u = *(const float4*)yr;
      float4 w = *(const float4*)(yr + 4);
      float2 z = *(const float2*)(yr + 8);
      sc[0] += u.x; sc[1] += u.y; sc[2] += u.z; sc[3] += u.w;
      sc[4] += w.x; sc[5] += w.y; sc[6] += w.z; sc[7] += w.w;
      sc[8] += z.x; sc[9] += z.y;
      dc += 1.f;
      e1 = v.x;
    }
    if (e2 >= 0) {
      int2 v = tn_i[e2];
      const float* yr = y_p + (size_t)v.y * YST;
      float4 u = *(const float4*)yr;
      float4 w = *(const float4*)(yr + 4);
      float2 z = *(const float2*)(yr + 8);
      sp[0] += u.x; sp[1] += u.y; sp[2] += u.z; sp[3] += u.w;
      sp[4] += w.x; sp[5] += w.y; sp[6] += w.z; sp[7] += w.w;
      sp[8] += z.x; sp[9] += z.y;
      dp += 1.f;
      e2 = v.x;
    }
  }

  float Gc = dc > 0.f ? 1.f : 0.f, Gp = dp > 0.f ? 1.f : 0.f;
  float ivc = 1.f / fmaxf(dc, 1.f), ivp = 1.f / fmaxf(dp, 1.f);

  const float4* xp4 = (const float4*)(xt + (size_t)t * 8);
  float4 xa = xp4[0], xb = xp4[1];
  float xv[8] = {xa.x, xa.y, xa.z, xa.w, xb.x, xb.y, xb.z, xb.w};

  float lg[OUTC];
  #pragma unroll
  for (int o = 0; o < OUTC; ++o)
    lg[o] = sc[o] * ivc + sp[o] * ivp +
            Gc * sB[80 + o] + Gp * sB[90 + o] + sB[100 + o];
  #pragma unroll
  for (int r = 0; r < 8; ++r) {
    float xr = xv[r];
    #pragma unroll
    for (int o = 0; o < OUTC; ++o) lg[o] += xr * sB[r * 10 + o];
  }

  float m = lg[0];
  #pragma unroll
  for (int o = 1; o < OUTC; ++o) m = fmaxf(m, lg[o]);
  float s = 0.f;
  #pragma unroll
  for (int o = 0; o < OUTC; ++o) { lg[o] = __expf(lg[o] - m); s += lg[o]; }
  float invs = 1.0f / s;
  float* op = &out[(size_t)t * OUTC];
  #pragma unroll
  for (int o = 0; o < 5; ++o) {
    float2 p2; p2.x = lg[2 * o] * invs; p2.y = lg[2 * o + 1] * invs;
    *(float2*)&op[2 * o] = p2;
  }
}

extern "C" void kernel_launch(void* const* d_in, const int* in_sizes, int n_in,
                              void* d_out, int out_size, void* d_ws, size_t ws_size,
                              hipStream_t stream) {
  const float* x_c   = (const float*)d_in[0];
  const float* x_t   = (const float*)d_in[1];
  const float* x_p   = (const float*)d_in[2];
  const float* W_col = (const float*)d_in[3];
  const float* b_col = (const float*)d_in[4];
  const float* Wn    = (const float*)d_in[5];
  const float* Wr    = (const float*)d_in[6];
  const float* b_lin = (const float*)d_in[7];
  const float* W_out = (const float*)d_in[8];
  const float* b_out = (const float*)d_in[9];
  const int* e_m_src = (const int*)d_in[10];
  const int* e_m_dst = (const int*)d_in[11];
  const int* e_i_src = (const int*)d_in[12];
  const int* e_i_dst = (const int*)d_in[13];
  float* out = (float*)d_out;

  // ---- workspace carve-out (~78 MB; ws_size = 256 MiB) ----
  size_t cursor = 0;
  char* base = (char*)d_ws;
  auto alloc = [&](size_t bytes) {
    void* p = base + cursor;
    cursor += (bytes + 255) & ~(size_t)255;
    return p;
  };
  int* heads   = (int*)alloc((size_t)NHEADS * 4);                  // 3.0 MB
  int* head_c  = heads;
  int* head_p  = heads + NCV;
  int* heads_t = heads + NCV + NPV;                                // int2-interleaved per t
  int4* cnm = (int4*)alloc((size_t)EMV * 64);                      // 19.2 MB (fat)
  int4* cni = (int4*)alloc((size_t)EIV * 64);                      // 38.4 MB (fat)
  int2* tn_m = (int2*)alloc((size_t)EMV * 8);                      // 2.4 MB
  int2* tn_i = (int2*)alloc((size_t)EIV * 8);                      // 4.8 MB
  float* y_c = (float*)alloc((size_t)NCV * YST * 4);               // 6.4 MB
  float* y_p = (float*)alloc((size_t)NPV * YST * 4);               // 3.2 MB
  float* T   = (float*)alloc(3 * 1280 * 4);
  float* Q   = (float*)alloc(7 * 1280 * 4);
  float* B   = (float*)alloc(450 * 4);

  const float* Wn_l[2][4]; const float* Wr_l[2][4];
  for (int l = 0; l < 2; ++l)
    for (int r = 0; r < 4; ++r) {
      Wn_l[l][r] = Wn + (size_t)(l * 4 + r) * DD * DD;
      Wr_l[l][r] = Wr + (size_t)(l * 4 + r) * DD * DD;
    }

  // ---- d1: heads init + prepT ----
  init_prepT<<<HIB + PTB, 256, 0, stream>>>(
      heads, Wn_l[1][0], Wn_l[1][2], Wr_l[1][0], Wr_l[1][2], W_out, T);

  // ---- d2: build (both sides in-thread, fat c/p + thin t nodes) + light prepQ tail ----
  build_prepQ<<<NEB + QB, 256, 0, stream>>>(
      e_m_src, e_m_dst, e_i_src, e_i_dst, x_t,
      head_c, head_p, heads_t, cnm, cni, tn_m, tn_i,
      Wn_l[0][1], Wr_l[0][1], Wn_l[0][3], Wr_l[0][3],
      Wn_l[0][0], Wn_l[0][2], Wr_l[0][0], Wr_l[0][2], T, Q);

  // ---- d3: prepB (tiny dedicated dispatch — r13 lesson: do NOT replicate per-block) ----
  prep_B_w<<<(450 * 64 + 255) / 256, 256, 0, stream>>>(
      W_col, b_col, b_lin, W_out, b_out, T, Q, B);

  // ---- d4: gather_y (walk fat c/p lists, B from global into LDS) ----
  gather_y<<<GYB, 256, 0, stream>>>(
      head_c, head_p, cnm, cni, x_c, x_p, B, y_c, y_p);

  // ---- d5: gather_t (dual thin walks + combine + softmax) ----
  gather_t<<<(NTV + 255) / 256, 256, 0, stream>>>(
      y_c, y_p, x_t, heads_t, tn_m, tn_i, B, out);
}